// Round 1
// baseline (11285.759 us; speedup 1.0000x reference)
//
#include <hip/hip_runtime.h>

// ODE_Vanilla scan: B=128, T=256, I=256, H=1024, C=10, fp32 throughout.
// Per step t:
//   phi = relu(h @ Wh + x_t @ Wx + b)       (phase 1, writes v = a*h - phi)
//   u   = v @ Wh^T                          (phase 2)
//   grad = a*v - (phi>0)*u ; h -= LR*grad ; out[b,t,:] += h_new @ fc_w (atomic)
// Kernel-boundary stream ordering provides the grid-wide sync between phases.

constexpr int Bsz = 128, Tn = 256, In = 256, Hn = 1024, Cn = 10;
constexpr float LR = 0.001f;

// ---- Wh -> Wh^T (once per launch) so phase 2 gets coalesced W[k][col] loads
__global__ __launch_bounds__(256) void k_transpose(const float* __restrict__ W,
                                                   float* __restrict__ WT) {
  __shared__ float tile[32][33];
  const int bx = blockIdx.x * 32, by = blockIdx.y * 32;
  const int tx = threadIdx.x & 31, ty = threadIdx.x >> 5;  // ty 0..7
#pragma unroll
  for (int dy = 0; dy < 32; dy += 8)
    tile[ty + dy][tx] = W[(size_t)(by + ty + dy) * Hn + bx + tx];
  __syncthreads();
#pragma unroll
  for (int dy = 0; dy < 32; dy += 8)
    WT[(size_t)(bx + ty + dy) * Hn + by + tx] = tile[tx][ty + dy];
}

// ---- init: d_out FC region = fc_b broadcast (atomics accumulate on top),
//            h_cur = hidden. Runs every call (ws/out re-poisoned by harness).
__global__ __launch_bounds__(256) void k_init(float* __restrict__ out,
                                              const float* __restrict__ fc_b,
                                              float* __restrict__ h_cur,
                                              const float* __restrict__ hidden) {
  const int i = blockIdx.x * blockDim.x + threadIdx.x;
  if (i < Bsz * Tn * Cn) out[i] = fc_b[i % Cn];
  if (i < Bsz * Hn) h_cur[i] = hidden[i];
}

// ---- phase 1: v = a*h - relu(h@Wh + x_t@Wx + b)
// grid 512 = rt(16, 8 rows) x ct(32, 32 cols); block 256 = (j in 32) x (r in 8)
__global__ __launch_bounds__(256) void k_phase1(
    const float* __restrict__ h, const float* __restrict__ X,
    const float* __restrict__ Wh, const float* __restrict__ Wx,
    const float* __restrict__ bias, const float* __restrict__ alpha,
    float* __restrict__ v_out, int t) {
  __shared__ float h_s[8][Hn];   // 32 KB
  __shared__ float x_s[8][In];   // 8 KB
  const int rt = blockIdx.x >> 5, ct = blockIdx.x & 31;
  const int r0 = rt * 8, c0 = ct * 32;
  const int tid = threadIdx.x;

  {  // stage 8 h rows (contiguous 8192 floats), coalesced float4
    const float4* src = (const float4*)(h + (size_t)r0 * Hn);
    float4* dst = (float4*)(&h_s[0][0]);
#pragma unroll
    for (int u = 0; u < 8; u++) dst[tid + 256 * u] = src[tid + 256 * u];
  }
  {  // stage 8 x_t rows (each row 256 floats contiguous)
#pragma unroll
    for (int u = 0; u < 2; u++) {
      const int idx = tid + 256 * u;  // 0..511
      const int rr = idx >> 6, ii = idx & 63;
      ((float4*)(&x_s[rr][0]))[ii] =
          ((const float4*)(X + ((size_t)(r0 + rr) * Tn + t) * In))[ii];
    }
  }
  __syncthreads();

  const int j = tid & 31, r = tid >> 5;
  const int col = c0 + j;  // lane j fastest -> coalesced W[k][col] loads
  float4 acc0 = {0, 0, 0, 0}, acc1 = {0, 0, 0, 0};  // 8 indep FMA chains
  const float4* hrow = (const float4*)(&h_s[r][0]);
  const float* W0 = Wh + col;
#pragma unroll 2
  for (int k4 = 0; k4 < 128; k4++) {
    const float4 ha = hrow[k4];
    const float4 hb = hrow[k4 + 128];
    const float* wa = W0 + (size_t)(k4 * 4) * Hn;
    const float* wb = W0 + (size_t)(k4 * 4 + 512) * Hn;
    acc0.x += ha.x * wa[0];
    acc0.y += ha.y * wa[Hn];
    acc0.z += ha.z * wa[2 * Hn];
    acc0.w += ha.w * wa[3 * Hn];
    acc1.x += hb.x * wb[0];
    acc1.y += hb.y * wb[Hn];
    acc1.z += hb.z * wb[2 * Hn];
    acc1.w += hb.w * wb[3 * Hn];
  }
  const float4* xrow = (const float4*)(&x_s[r][0]);
  const float* Wx0 = Wx + col;
#pragma unroll 2
  for (int i4 = 0; i4 < 32; i4++) {
    const float4 xa = xrow[i4];
    const float4 xb = xrow[i4 + 32];
    const float* wa = Wx0 + (size_t)(i4 * 4) * Hn;
    const float* wb = Wx0 + (size_t)(i4 * 4 + 128) * Hn;
    acc0.x += xa.x * wa[0];
    acc0.y += xa.y * wa[Hn];
    acc0.z += xa.z * wa[2 * Hn];
    acc0.w += xa.w * wa[3 * Hn];
    acc1.x += xb.x * wb[0];
    acc1.y += xb.y * wb[Hn];
    acc1.z += xb.z * wb[2 * Hn];
    acc1.w += xb.w * wb[3 * Hn];
  }
  const float pre = (acc0.x + acc0.y + acc0.z + acc0.w) +
                    (acc1.x + acc1.y + acc1.z + acc1.w) + bias[col];
  const float phi = fmaxf(pre, 0.f);
  const float av = alpha[0];
  v_out[(size_t)(r0 + r) * Hn + col] = av * h_s[r][col] - phi;
}

// ---- phase 2: u = v@Wh^T; grad = a*v - (phi>0)*u; h -= LR*grad;
//      fused FC partial: out[b,t,c] += sum_j h_new[b,j]*fc_w[j,c] (atomic)
__global__ __launch_bounds__(256) void k_phase2(
    float* __restrict__ h, const float* __restrict__ v_in,
    const float* __restrict__ WT, const float* __restrict__ alpha,
    const float* __restrict__ fc_w, float* __restrict__ out,
    float* __restrict__ hfin, int t, int last) {
  __shared__ float v_s[8][Hn];   // 32 KB
  __shared__ float hn_s[8][32];
  const int rt = blockIdx.x >> 5, ct = blockIdx.x & 31;
  const int r0 = rt * 8, c0 = ct * 32;
  const int tid = threadIdx.x;
  {
    const float4* src = (const float4*)(v_in + (size_t)r0 * Hn);
    float4* dst = (float4*)(&v_s[0][0]);
#pragma unroll
    for (int u = 0; u < 8; u++) dst[tid + 256 * u] = src[tid + 256 * u];
  }
  __syncthreads();

  const int j = tid & 31, r = tid >> 5;
  const int col = c0 + j;
  float4 acc0 = {0, 0, 0, 0}, acc1 = {0, 0, 0, 0};
  const float4* vrow = (const float4*)(&v_s[r][0]);
  const float* W0 = WT + col;
#pragma unroll 2
  for (int k4 = 0; k4 < 128; k4++) {
    const float4 va = vrow[k4];
    const float4 vb = vrow[k4 + 128];
    const float* wa = W0 + (size_t)(k4 * 4) * Hn;
    const float* wb = W0 + (size_t)(k4 * 4 + 512) * Hn;
    acc0.x += va.x * wa[0];
    acc0.y += va.y * wa[Hn];
    acc0.z += va.z * wa[2 * Hn];
    acc0.w += va.w * wa[3 * Hn];
    acc1.x += vb.x * wb[0];
    acc1.y += vb.y * wb[Hn];
    acc1.z += vb.z * wb[2 * Hn];
    acc1.w += vb.w * wb[3 * Hn];
  }
  const float u_val = (acc0.x + acc0.y + acc0.z + acc0.w) +
                      (acc1.x + acc1.y + acc1.z + acc1.w);
  const float av = alpha[0];
  const float vv = v_s[r][col];
  const size_t hidx = (size_t)(r0 + r) * Hn + col;
  const float hv = h[hidx];
  const float phi = av * hv - vv;  // phi = a*h - v  (exact reconstruction)
  const float grad = av * vv - (phi > 0.f ? u_val : 0.f);
  const float hn = hv - LR * grad;
  h[hidx] = hn;              // in-place safe: each element owned by one thread
  if (last) hfin[hidx] = hn; // h_final output region
  hn_s[r][j] = hn;
  __syncthreads();
  // per-block FC reduction over this block's 32 columns -> 80 atomics
  if (tid < 80) {
    const int rr = tid / 10, c = tid % 10;
    float s = 0.f;
#pragma unroll
    for (int jj = 0; jj < 32; jj++)
      s += hn_s[rr][jj] * fc_w[(size_t)(c0 + jj) * Cn + c];
    atomicAdd(&out[((size_t)(r0 + rr) * Tn + t) * Cn + c], s);
  }
}

extern "C" void kernel_launch(void* const* d_in, const int* in_sizes, int n_in,
                              void* d_out, int out_size, void* d_ws, size_t ws_size,
                              hipStream_t stream) {
  const float* X      = (const float*)d_in[0];  // (B,T,I)
  const float* hidden = (const float*)d_in[1];  // (B,H)
  const float* alpha  = (const float*)d_in[2];  // (1,)
  const float* bias   = (const float*)d_in[3];  // (H,)
  const float* Wh     = (const float*)d_in[4];  // (H,H)
  const float* Wx     = (const float*)d_in[5];  // (I,H)
  const float* fc_w   = (const float*)d_in[6];  // (H,C)
  const float* fc_b   = (const float*)d_in[7];  // (C,)
  float* out  = (float*)d_out;                  // (B*T,C) then (B,H)
  float* hfin = out + (size_t)Bsz * Tn * Cn;

  char* ws = (char*)d_ws;                       // needs ~5 MB
  float* WhT   = (float*)ws;                                  // 4 MB
  float* h_cur = (float*)(ws + (size_t)Hn * Hn * sizeof(float));
  float* v_buf = h_cur + (size_t)Bsz * Hn;

  k_transpose<<<dim3(32, 32), 256, 0, stream>>>(Wh, WhT);
  k_init<<<(Bsz * Tn * Cn + 255) / 256, 256, 0, stream>>>(out, fc_b, h_cur, hidden);
  for (int t = 0; t < Tn; t++) {
    k_phase1<<<512, 256, 0, stream>>>(h_cur, X, Wh, Wx, bias, alpha, v_buf, t);
    k_phase2<<<512, 256, 0, stream>>>(h_cur, v_buf, WhT, alpha, fc_w, out, hfin,
                                      t, t == Tn - 1);
  }
}

// Round 2
// 10920.297 us; speedup vs baseline: 1.0335x; 1.0335x over previous
//
#include <hip/hip_runtime.h>

// ODE_Vanilla scan: B=128, T=256, I=256, H=1024, C=10, fp32 throughout.
// Per step t:
//   phase1: v = a*h - relu(h@Wh + x_t@Wx + b)
//   phase2: u = v@Wh^T; grad = a*v - (phi>0)*u; h -= LR*grad; out[b,t,:] += h@fc_w
// R2: float4 W loads (4 cols/thread), 8-way in-block split-K with shuffle
// reduction, 1024 blocks (4/CU, zero tail), LDS chunk-swizzle for bank spread.

constexpr int Bsz = 128, Tn = 256, In = 256, Hn = 1024, Cn = 10;
constexpr float LR = 0.001f;
constexpr int HP = 1024 + 32;  // 8 chunks of 128, each padded +4 floats
#define HSW(k) ((k) + (((k) >> 7) << 2))  // swizzled LDS index

__global__ __launch_bounds__(256) void k_transpose(const float* __restrict__ W,
                                                   float* __restrict__ WT) {
  __shared__ float tile[32][33];
  const int bx = blockIdx.x * 32, by = blockIdx.y * 32;
  const int tx = threadIdx.x & 31, ty = threadIdx.x >> 5;
#pragma unroll
  for (int dy = 0; dy < 32; dy += 8)
    tile[ty + dy][tx] = W[(size_t)(by + ty + dy) * Hn + bx + tx];
  __syncthreads();
#pragma unroll
  for (int dy = 0; dy < 32; dy += 8)
    WT[(size_t)(bx + ty + dy) * Hn + by + tx] = tile[tx][ty + dy];
}

__global__ __launch_bounds__(256) void k_init(float* __restrict__ out,
                                              const float* __restrict__ fc_b,
                                              float* __restrict__ h_cur,
                                              const float* __restrict__ hidden) {
  const int i = blockIdx.x * blockDim.x + threadIdx.x;
  if (i < Bsz * Tn * Cn) out[i] = fc_b[i % Cn];
  if (i < Bsz * Hn) h_cur[i] = hidden[i];
}

__device__ __forceinline__ void fma4(float4& a, float s, const float4& w) {
  a.x = fmaf(s, w.x, a.x);
  a.y = fmaf(s, w.y, a.y);
  a.z = fmaf(s, w.z, a.z);
  a.w = fmaf(s, w.w, a.w);
}

__device__ __forceinline__ void red_ks(float4& a) {
#pragma unroll
  for (int m = 4; m <= 16; m <<= 1) {  // ks lives in lane bits 2..4
    a.x += __shfl_xor(a.x, m, 64);
    a.y += __shfl_xor(a.y, m, 64);
    a.z += __shfl_xor(a.z, m, 64);
    a.w += __shfl_xor(a.w, m, 64);
  }
}

// grid 1024 = rt(16, 8 rows) x ct(64, 16 cols); thread = c4(4) x ks(8) x r(8)
__global__ __launch_bounds__(256, 4) void k_phase1(
    const float* __restrict__ h, const float* __restrict__ X,
    const float* __restrict__ Wh, const float* __restrict__ Wx,
    const float* __restrict__ bias, const float* __restrict__ alpha,
    float* __restrict__ v_out, int t) {
  __shared__ float h_s[8][HP];  // 33 KB -> 4 blocks/CU
  const int ct = blockIdx.x & 63, rt = blockIdx.x >> 6;
  const int c0 = ct * 16, r0 = rt * 8;
  const int tid = threadIdx.x;
  {  // stage 8 h rows (8192 contiguous floats), swizzled LDS layout
    const float4* src = (const float4*)(h + (size_t)r0 * Hn);
#pragma unroll
    for (int u = 0; u < 8; u++) {
      const int f = tid + 256 * u;
      const int row = f >> 8, k = (f & 255) * 4;
      *(float4*)&h_s[row][HSW(k)] = src[f];
    }
  }
  __syncthreads();

  const int c4 = tid & 3, ks = (tid >> 2) & 7, r = tid >> 5;
  const int col = c0 + 4 * c4;
  float4 aA = {0, 0, 0, 0}, aB = {0, 0, 0, 0};
  {  // Wh part: K-chunk [ks*128, ks*128+128)
    const float* hr = &h_s[r][ks * 132];
    const float* Wp = Wh + (size_t)(ks * 128) * Hn + col;
#pragma unroll 2
    for (int q = 0; q < 32; q++) {
      const float4 h4 = *(const float4*)(hr + 4 * q);
      const float4 w0 = *(const float4*)(Wp);
      const float4 w1 = *(const float4*)(Wp + Hn);
      const float4 w2 = *(const float4*)(Wp + 2 * Hn);
      const float4 w3 = *(const float4*)(Wp + 3 * Hn);
      Wp += 4 * Hn;
      fma4(aA, h4.x, w0);
      fma4(aA, h4.y, w1);
      fma4(aB, h4.z, w2);
      fma4(aB, h4.w, w3);
    }
  }
  {  // Wx part: I-chunk [ks*32, ks*32+32), x straight from global (L2-hot)
    const float* xp = X + ((size_t)(r0 + r) * Tn + t) * In + ks * 32;
    const float* Wp = Wx + (size_t)(ks * 32) * Hn + col;
#pragma unroll 2
    for (int q = 0; q < 8; q++) {
      const float4 x4 = *(const float4*)(xp + 4 * q);
      const float4 w0 = *(const float4*)(Wp);
      const float4 w1 = *(const float4*)(Wp + Hn);
      const float4 w2 = *(const float4*)(Wp + 2 * Hn);
      const float4 w3 = *(const float4*)(Wp + 3 * Hn);
      Wp += 4 * Hn;
      fma4(aA, x4.x, w0);
      fma4(aA, x4.y, w1);
      fma4(aB, x4.z, w2);
      fma4(aB, x4.w, w3);
    }
  }
  float4 acc = {aA.x + aB.x, aA.y + aB.y, aA.z + aB.z, aA.w + aB.w};
  red_ks(acc);
  if (ks == 0) {
    const float4 b4 = *(const float4*)(bias + col);
    const float av = alpha[0];
    const float4 hv = *(const float4*)(&h_s[r][HSW(col)]);
    float4 v;
    v.x = av * hv.x - fmaxf(acc.x + b4.x, 0.f);
    v.y = av * hv.y - fmaxf(acc.y + b4.y, 0.f);
    v.z = av * hv.z - fmaxf(acc.z + b4.z, 0.f);
    v.w = av * hv.w - fmaxf(acc.w + b4.w, 0.f);
    *(float4*)(v_out + (size_t)(r0 + r) * Hn + col) = v;
  }
}

__global__ __launch_bounds__(256, 4) void k_phase2(
    float* __restrict__ h, const float* __restrict__ v_in,
    const float* __restrict__ WT, const float* __restrict__ alpha,
    const float* __restrict__ fc_w, float* __restrict__ out,
    float* __restrict__ hfin, int t, int last) {
  __shared__ float v_s[8][HP];
  __shared__ float hn_s[8][16];
  const int ct = blockIdx.x & 63, rt = blockIdx.x >> 6;
  const int c0 = ct * 16, r0 = rt * 8;
  const int tid = threadIdx.x;
  {
    const float4* src = (const float4*)(v_in + (size_t)r0 * Hn);
#pragma unroll
    for (int u = 0; u < 8; u++) {
      const int f = tid + 256 * u;
      const int row = f >> 8, k = (f & 255) * 4;
      *(float4*)&v_s[row][HSW(k)] = src[f];
    }
  }
  __syncthreads();

  const int c4 = tid & 3, ks = (tid >> 2) & 7, r = tid >> 5;
  const int col = c0 + 4 * c4;
  float4 aA = {0, 0, 0, 0}, aB = {0, 0, 0, 0};
  {
    const float* vr = &v_s[r][ks * 132];
    const float* Wp = WT + (size_t)(ks * 128) * Hn + col;
#pragma unroll 2
    for (int q = 0; q < 32; q++) {
      const float4 v4 = *(const float4*)(vr + 4 * q);
      const float4 w0 = *(const float4*)(Wp);
      const float4 w1 = *(const float4*)(Wp + Hn);
      const float4 w2 = *(const float4*)(Wp + 2 * Hn);
      const float4 w3 = *(const float4*)(Wp + 3 * Hn);
      Wp += 4 * Hn;
      fma4(aA, v4.x, w0);
      fma4(aA, v4.y, w1);
      fma4(aB, v4.z, w2);
      fma4(aB, v4.w, w3);
    }
  }
  float4 acc = {aA.x + aB.x, aA.y + aB.y, aA.z + aB.z, aA.w + aB.w};
  red_ks(acc);
  if (ks == 0) {
    const float av = alpha[0];
    const float4 vv = *(const float4*)(&v_s[r][HSW(col)]);
    const size_t hoff = (size_t)(r0 + r) * Hn + col;
    const float4 hv = *(const float4*)(h + hoff);
    float4 hn;  // phi = a*h - v; grad = a*v - (phi>0)*u; hn = h - LR*grad
    hn.x = hv.x - LR * (av * vv.x - ((av * hv.x - vv.x) > 0.f ? acc.x : 0.f));
    hn.y = hv.y - LR * (av * vv.y - ((av * hv.y - vv.y) > 0.f ? acc.y : 0.f));
    hn.z = hv.z - LR * (av * vv.z - ((av * hv.z - vv.z) > 0.f ? acc.z : 0.f));
    hn.w = hv.w - LR * (av * vv.w - ((av * hv.w - vv.w) > 0.f ? acc.w : 0.f));
    *(float4*)(h + hoff) = hn;
    if (last) *(float4*)(hfin + hoff) = hn;
    *(float4*)&hn_s[r][4 * c4] = hn;
  }
  __syncthreads();
  if (tid < 80) {  // FC partial over this block's 16 cols -> 80 atomics
    const int rr = tid / 10, c = tid % 10;
    float s = 0.f;
#pragma unroll
    for (int jj = 0; jj < 16; jj++)
      s += hn_s[rr][jj] * fc_w[(size_t)(c0 + jj) * Cn + c];
    atomicAdd(&out[((size_t)(r0 + rr) * Tn + t) * Cn + c], s);
  }
}

extern "C" void kernel_launch(void* const* d_in, const int* in_sizes, int n_in,
                              void* d_out, int out_size, void* d_ws, size_t ws_size,
                              hipStream_t stream) {
  const float* X      = (const float*)d_in[0];
  const float* hidden = (const float*)d_in[1];
  const float* alpha  = (const float*)d_in[2];
  const float* bias   = (const float*)d_in[3];
  const float* Wh     = (const float*)d_in[4];
  const float* Wx     = (const float*)d_in[5];
  const float* fc_w   = (const float*)d_in[6];
  const float* fc_b   = (const float*)d_in[7];
  float* out  = (float*)d_out;
  float* hfin = out + (size_t)Bsz * Tn * Cn;

  char* ws = (char*)d_ws;
  float* WhT   = (float*)ws;  // 4 MB
  float* h_cur = (float*)(ws + (size_t)Hn * Hn * sizeof(float));
  float* v_buf = h_cur + (size_t)Bsz * Hn;

  k_transpose<<<dim3(32, 32), 256, 0, stream>>>(Wh, WhT);
  k_init<<<(Bsz * Tn * Cn + 255) / 256, 256, 0, stream>>>(out, fc_b, h_cur, hidden);
  for (int t = 0; t < Tn; t++) {
    k_phase1<<<1024, 256, 0, stream>>>(h_cur, X, Wh, Wx, bias, alpha, v_buf, t);
    k_phase2<<<1024, 256, 0, stream>>>(h_cur, v_buf, WhT, alpha, fc_w, out, hfin,
                                       t, t == Tn - 1);
  }
}